// Round 2
// baseline (2118.710 us; speedup 1.0000x reference)
//
#include <hip/hip_runtime.h>
#include <hip/hip_bf16.h>

#define N   128
#define N3  (N*N*N)
#define M   64
#define M3  (M*M*M)
#define NPTS 65536

// float offsets inside the converted-weights buffer
enum : int {
  OW0A = 0,                 // 16*3*27   = 1296
  OW0B = 1296,              // 16*16*27  = 6912
  OWD0 = 8208,              // 32*16*27  = 13824
  OW1A = 22032,             // 32*32*27  = 27648
  OW1B = 49680,             // 32*32*27  = 27648
  OS0A = 77328, OB0A = 77344,
  OS0B = 77360, OB0B = 77376,
  OSD0 = 77392, OBD0 = 77424,
  OS1A = 77456, OB1A = 77488,
  OS1B = 77520, OB1B = 77552,
  WTOT = 77584
};

__device__ __forceinline__ float ldT(const float* p) { return *p; }
__device__ __forceinline__ float ldT(const __hip_bfloat16* p) { return __bfloat162float(*p); }
__device__ __forceinline__ void stT(float* p, float v) { *p = v; }
__device__ __forceinline__ void stT(__hip_bfloat16* p, float v) { *p = __float2bfloat16(v); }

// read element i of an input whose dtype is decided at runtime (bf=1 -> bf16)
__device__ __forceinline__ float ldIn(const void* p, long i, int bf) {
  return bf ? __bfloat162float(((const __hip_bfloat16*)p)[i]) : ((const float*)p)[i];
}

// ---- dtype probe: s0a ~ uniform(0.5,1.5). If bf16-packed, byte1 of every
// 32-bit word is 0x3F (bf16 exponent of [0.5,1.5]); if fp32, it's random
// mantissa bits. 16 elements -> inspect first 8 words (32 bytes, safe both ways).
__global__ void probe_k(const unsigned* __restrict__ s0a_raw, int* __restrict__ flag) {
  if (threadIdx.x == 0 && blockIdx.x == 0) {
    int all = 1;
    for (int i = 0; i < 8; ++i) {
      unsigned w = s0a_raw[i];
      if (((w >> 8) & 0xFFu) != 0x3Fu) all = 0;
    }
    *flag = all;   // 1 = bf16 inputs, 0 = fp32 inputs
  }
}

// ---- convert all weights/scales/shifts (either dtype) to one fp32 buffer ----
__global__ __launch_bounds__(256) void cvt_k(
    const void* w0a, const void* w0b, const void* wd0,
    const void* w1a, const void* w1b,
    const void* s0a, const void* b0a,
    const void* s0b, const void* b0b,
    const void* sd0, const void* bd0,
    const void* s1a, const void* b1a,
    const void* s1b, const void* b1b,
    const int* __restrict__ flag, float* __restrict__ wbuf)
{
  int i = blockIdx.x * 256 + threadIdx.x;
  if (i >= WTOT) return;
  int bf = *flag;
  const void* src; int off;
  if      (i < OW0B) { src = w0a; off = OW0A; }
  else if (i < OWD0) { src = w0b; off = OW0B; }
  else if (i < OW1A) { src = wd0; off = OWD0; }
  else if (i < OW1B) { src = w1a; off = OW1A; }
  else if (i < OS0A) { src = w1b; off = OW1B; }
  else if (i < OB0A) { src = s0a; off = OS0A; }
  else if (i < OS0B) { src = b0a; off = OB0A; }
  else if (i < OB0B) { src = s0b; off = OS0B; }
  else if (i < OSD0) { src = b0b; off = OB0B; }
  else if (i < OBD0) { src = sd0; off = OSD0; }
  else if (i < OS1A) { src = bd0; off = OBD0; }
  else if (i < OB1A) { src = s1a; off = OS1A; }
  else if (i < OS1B) { src = b1a; off = OB1A; }
  else if (i < OB1B) { src = s1b; off = OS1B; }
  else               { src = b1b; off = OB1B; }
  wbuf[i] = ldIn(src, i - off, bf);
}

// ---- active-voxel list from mask (order irrelevant) ----
__global__ __launch_bounds__(256) void masklist_k(const int* __restrict__ mask,
                                                  int* __restrict__ list,
                                                  int* __restrict__ cnt)
{
  int idx = blockIdx.x * 256 + threadIdx.x;
  if (idx >= N3) return;
  if (mask[idx]) { int p = atomicAdd(cnt, 1); list[p] = idx; }
}

// ---- m1 = maxpool3d(mask, 3, stride 2, pad 1) ----
__global__ __launch_bounds__(256) void dsmask_k(const int* __restrict__ mask,
                                                int* __restrict__ m1)
{
  int idx = blockIdx.x * 256 + threadIdx.x;
  if (idx >= M3) return;
  int z = idx >> 12, y = (idx >> 6) & 63, x = idx & 63;
  int r = 0;
  #pragma unroll
  for (int dz = 0; dz < 3; ++dz) {
    int iz = 2 * z + dz - 1;
    if ((unsigned)iz >= 128u) continue;
    #pragma unroll
    for (int dy = 0; dy < 3; ++dy) {
      int iy = 2 * y + dy - 1;
      if ((unsigned)iy >= 128u) continue;
      #pragma unroll
      for (int dx = 0; dx < 3; ++dx) {
        int ix = 2 * x + dx - 1;
        if ((unsigned)ix >= 128u) continue;
        r |= mask[(iz << 14) | (iy << 7) | ix];
      }
    }
  }
  m1[idx] = r;
}

// ---- conv0a: 3->16 at active voxels only (input = x_feat * mask) ----
template <typename T>
__global__ __launch_bounds__(256) void conv0a_k(
    const void* __restrict__ xf, const int* __restrict__ flag,
    const int* __restrict__ mask,
    const int* __restrict__ list, const int* __restrict__ cnt,
    const float* __restrict__ wbuf, T* __restrict__ h0)
{
  int i = blockIdx.x * 256 + threadIdx.x;
  if (i >= *cnt) return;
  int bf = *flag;
  int idx = list[i];
  int z = idx >> 14, y = (idx >> 7) & 127, x = idx & 127;
  float v[3][27];
  #pragma unroll
  for (int dz = 0; dz < 3; ++dz)
  #pragma unroll
  for (int dy = 0; dy < 3; ++dy)
  #pragma unroll
  for (int dx = 0; dx < 3; ++dx) {
    int k = dz * 9 + dy * 3 + dx;
    int iz = z + dz - 1, iy = y + dy - 1, ix = x + dx - 1;
    bool ok = (unsigned)iz < 128u && (unsigned)iy < 128u && (unsigned)ix < 128u;
    int t = ok ? ((iz << 14) | (iy << 7) | ix) : 0;
    bool act = ok && (mask[t] != 0);
    v[0][k] = act ? ldIn(xf, t, bf) : 0.f;
    v[1][k] = act ? ldIn(xf, (long)N3 + t, bf) : 0.f;
    v[2][k] = act ? ldIn(xf, 2l * N3 + t, bf) : 0.f;
  }
  #pragma unroll
  for (int oc = 0; oc < 16; ++oc) {
    float acc = 0.f;
    #pragma unroll
    for (int ic = 0; ic < 3; ++ic) {
      const float* w = wbuf + OW0A + (oc * 3 + ic) * 27;
      #pragma unroll
      for (int k = 0; k < 27; ++k) acc = fmaf(w[k], v[ic][k], acc);
    }
    float r = fmaxf(fmaf(acc, wbuf[OS0A + oc], wbuf[OB0A + oc]), 0.f);
    stT(h0 + (size_t)oc * N3 + idx, r);
  }
}

// ---- conv0b: 16->16 at active voxels only ----
template <typename T>
__global__ __launch_bounds__(256) void conv0b_k(
    const T* __restrict__ h0, const int* __restrict__ list, const int* __restrict__ cnt,
    const float* __restrict__ wbuf, T* __restrict__ h1)
{
  int i = blockIdx.x * 256 + threadIdx.x;
  if (i >= *cnt) return;
  int idx = list[i];
  int z = idx >> 14, y = (idx >> 7) & 127, x = idx & 127;
  int toff[27]; bool tv[27];
  #pragma unroll
  for (int dz = 0; dz < 3; ++dz)
  #pragma unroll
  for (int dy = 0; dy < 3; ++dy)
  #pragma unroll
  for (int dx = 0; dx < 3; ++dx) {
    int k = dz * 9 + dy * 3 + dx;
    int iz = z + dz - 1, iy = y + dy - 1, ix = x + dx - 1;
    bool ok = (unsigned)iz < 128u && (unsigned)iy < 128u && (unsigned)ix < 128u;
    tv[k] = ok;
    toff[k] = ok ? ((iz << 14) | (iy << 7) | ix) : 0;
  }
  float acc[16];
  #pragma unroll
  for (int oc = 0; oc < 16; ++oc) acc[oc] = 0.f;
  for (int ic = 0; ic < 16; ++ic) {
    float t[27];
    #pragma unroll
    for (int k = 0; k < 27; ++k) t[k] = tv[k] ? ldT(h0 + (size_t)ic * N3 + toff[k]) : 0.f;
    #pragma unroll
    for (int oc = 0; oc < 16; ++oc) {
      const float* w = wbuf + OW0B + (oc * 16 + ic) * 27;
      #pragma unroll
      for (int k = 0; k < 27; ++k) acc[oc] = fmaf(w[k], t[k], acc[oc]);
    }
  }
  #pragma unroll
  for (int oc = 0; oc < 16; ++oc) {
    float r = fmaxf(fmaf(acc[oc], wbuf[OS0B + oc], wbuf[OB0B + oc]), 0.f);
    stT(h1 + (size_t)oc * N3 + idx, r);
  }
}

// ---- convd0: 16->32, stride 2, dense over 64^3 (skip m1==0) ----
template <typename T>
__global__ __launch_bounds__(256) void convd0_k(
    const T* __restrict__ h1, const int* __restrict__ m1,
    const float* __restrict__ wbuf, float* __restrict__ hd)
{
  int idx = blockIdx.x * 256 + threadIdx.x;
  if (idx >= M3) return;
  if (!m1[idx]) {
    #pragma unroll
    for (int oc = 0; oc < 32; ++oc) hd[(size_t)oc * M3 + idx] = 0.f;
    return;
  }
  int z = idx >> 12, y = (idx >> 6) & 63, x = idx & 63;
  int toff[27]; bool tv[27];
  #pragma unroll
  for (int dz = 0; dz < 3; ++dz)
  #pragma unroll
  for (int dy = 0; dy < 3; ++dy)
  #pragma unroll
  for (int dx = 0; dx < 3; ++dx) {
    int k = dz * 9 + dy * 3 + dx;
    int iz = 2 * z + dz - 1, iy = 2 * y + dy - 1, ix = 2 * x + dx - 1;
    bool ok = (unsigned)iz < 128u && (unsigned)iy < 128u && (unsigned)ix < 128u;
    tv[k] = ok;
    toff[k] = ok ? ((iz << 14) | (iy << 7) | ix) : 0;
  }
  float acc[32];
  #pragma unroll
  for (int oc = 0; oc < 32; ++oc) acc[oc] = 0.f;
  for (int ic = 0; ic < 16; ++ic) {
    float t[27];
    #pragma unroll
    for (int k = 0; k < 27; ++k) t[k] = tv[k] ? ldT(h1 + (size_t)ic * N3 + toff[k]) : 0.f;
    #pragma unroll
    for (int oc = 0; oc < 32; ++oc) {
      const float* w = wbuf + OWD0 + (oc * 16 + ic) * 27;
      #pragma unroll
      for (int k = 0; k < 27; ++k) acc[oc] = fmaf(w[k], t[k], acc[oc]);
    }
  }
  #pragma unroll
  for (int oc = 0; oc < 32; ++oc)
    hd[(size_t)oc * M3 + idx] = fmaxf(fmaf(acc[oc], wbuf[OSD0 + oc], wbuf[OBD0 + oc]), 0.f);
}

// ---- conv1: 32->32 at 64^3 (used for w1a and w1b) ----
__global__ __launch_bounds__(256) void conv1_k(
    const float* __restrict__ hin, const int* __restrict__ m1,
    const float* __restrict__ wbuf, int wof, int sof, int bof,
    float* __restrict__ hout)
{
  int idx = blockIdx.x * 256 + threadIdx.x;
  if (idx >= M3) return;
  if (!m1[idx]) {
    #pragma unroll
    for (int oc = 0; oc < 32; ++oc) hout[(size_t)oc * M3 + idx] = 0.f;
    return;
  }
  int z = idx >> 12, y = (idx >> 6) & 63, x = idx & 63;
  int toff[27]; bool tv[27];
  #pragma unroll
  for (int dz = 0; dz < 3; ++dz)
  #pragma unroll
  for (int dy = 0; dy < 3; ++dy)
  #pragma unroll
  for (int dx = 0; dx < 3; ++dx) {
    int k = dz * 9 + dy * 3 + dx;
    int iz = z + dz - 1, iy = y + dy - 1, ix = x + dx - 1;
    bool ok = (unsigned)iz < 64u && (unsigned)iy < 64u && (unsigned)ix < 64u;
    tv[k] = ok;
    toff[k] = ok ? ((iz << 12) | (iy << 6) | ix) : 0;
  }
  float acc[32];
  #pragma unroll
  for (int oc = 0; oc < 32; ++oc) acc[oc] = 0.f;
  for (int ic = 0; ic < 32; ++ic) {
    float t[27];
    #pragma unroll
    for (int k = 0; k < 27; ++k) t[k] = tv[k] ? hin[(size_t)ic * M3 + toff[k]] : 0.f;
    #pragma unroll
    for (int oc = 0; oc < 32; ++oc) {
      const float* w = wbuf + wof + (oc * 32 + ic) * 27;
      #pragma unroll
      for (int k = 0; k < 27; ++k) acc[oc] = fmaf(w[k], t[k], acc[oc]);
    }
  }
  #pragma unroll
  for (int oc = 0; oc < 32; ++oc)
    hout[(size_t)oc * M3 + idx] = fmaxf(fmaf(acc[oc], wbuf[sof + oc], wbuf[bof + oc]), 0.f);
}

// ---- trilinear sample + transpose-store (dtype-flag aware on both ends) ----
__global__ __launch_bounds__(256) void sample_k(
    const void* __restrict__ coords, const int* __restrict__ flag,
    const float* __restrict__ vol, void* __restrict__ out)
{
  int p = blockIdx.x * 256 + threadIdx.x;
  if (p >= NPTS) return;
  int bf = *flag;
  float cx = ldIn(coords, 3l * p + 0, bf);
  float cy = ldIn(coords, 3l * p + 1, bf);
  float cz = ldIn(coords, 3l * p + 2, bf);
  float fx = (cx + 1.f) * 0.5f * 63.f;
  float fy = (cy + 1.f) * 0.5f * 63.f;
  float fz = (cz + 1.f) * 0.5f * 63.f;
  float x0f = floorf(fx), y0f = floorf(fy), z0f = floorf(fz);
  int x0 = (int)x0f, y0 = (int)y0f, z0 = (int)z0f;
  float tx = fx - x0f, ty = fy - y0f, tz = fz - z0f;
  int li[8]; float wt[8];
  #pragma unroll
  for (int dz = 0; dz < 2; ++dz)
  #pragma unroll
  for (int dy = 0; dy < 2; ++dy)
  #pragma unroll
  for (int dx = 0; dx < 2; ++dx) {
    int t = dz * 4 + dy * 2 + dx;
    int xi = x0 + dx, yi = y0 + dy, zi = z0 + dz;
    bool ok = (unsigned)xi < 64u && (unsigned)yi < 64u && (unsigned)zi < 64u;
    int xc = min(max(xi, 0), 63), yc = min(max(yi, 0), 63), zc = min(max(zi, 0), 63);
    li[t] = (zc << 12) | (yc << 6) | xc;
    float w = (dx ? tx : 1.f - tx) * (dy ? ty : 1.f - ty) * (dz ? tz : 1.f - tz);
    wt[t] = ok ? w : 0.f;
  }
  for (int c = 0; c < 32; ++c) {
    const float* v = vol + (size_t)c * M3;
    float s = 0.f;
    #pragma unroll
    for (int t = 0; t < 8; ++t) s += v[li[t]] * wt[t];
    if (bf) ((__hip_bfloat16*)out)[(size_t)p * 32 + c] = __float2bfloat16(s);
    else    ((float*)out)[(size_t)p * 32 + c] = s;
  }
}

extern "C" void kernel_launch(void* const* d_in, const int* in_sizes, int n_in,
                              void* d_out, int out_size, void* d_ws, size_t ws_size,
                              hipStream_t stream)
{
  const void* xf     = d_in[0];
  const int*  mask   = (const int*)d_in[1];
  const void* coords = d_in[2];
  const void* w0a = d_in[3];
  const void* s0a = d_in[4];
  const void* b0a = d_in[5];
  const void* w0b = d_in[6];
  const void* s0b = d_in[7];
  const void* b0b = d_in[8];
  const void* wd0 = d_in[9];
  const void* sd0 = d_in[10];
  const void* bd0 = d_in[11];
  const void* w1a = d_in[12];
  const void* s1a = d_in[13];
  const void* b1a = d_in[14];
  const void* w1b = d_in[15];
  const void* s1b = d_in[16];
  const void* b1b = d_in[17];

  char* ws = (char*)d_ws;
  size_t cur = 0;
  auto alloc = [&](size_t bytes) -> size_t {
    size_t o = cur; cur = (cur + bytes + 255) & ~(size_t)255; return o;
  };
  size_t o_flag = alloc(4);
  size_t o_cnt  = alloc(4);
  size_t o_list = alloc((size_t)N3 * 4);
  size_t o_m1   = alloc((size_t)M3 * 4);
  size_t o_wbuf = alloc((size_t)WTOT * 4);
  size_t fixed = cur;
  // fp32 intermediates if workspace allows, else bf16
  bool fp32path = (fixed + 2ull * 16 * N3 * sizeof(float) + (1u << 20)) <= ws_size;
  size_t elt = fp32path ? 4 : 2;
  size_t o_A = alloc((size_t)16 * N3 * elt);
  size_t o_B = alloc((size_t)16 * N3 * elt);

  int*   flag = (int*)(ws + o_flag);
  int*   cnt  = (int*)(ws + o_cnt);
  int*   list = (int*)(ws + o_list);
  int*   m1   = (int*)(ws + o_m1);
  float* wbuf = (float*)(ws + o_wbuf);
  // 64^3 stage buffers (always fp32) alias the big A/B regions:
  // hd in A (h0 dead), h2 in B (h1 dead), h3 in A (hd dead after conv1#1... h3 written by conv1#2 reading h2).
  float* hd = (float*)(ws + o_A);
  float* h2 = (float*)(ws + o_B);
  float* h3 = (float*)(ws + o_A);

  hipMemsetAsync(cnt, 0, 4, stream);
  hipMemsetAsync(ws + o_A, 0, (size_t)16 * N3 * elt, stream);
  hipMemsetAsync(ws + o_B, 0, (size_t)16 * N3 * elt, stream);

  probe_k<<<1, 64, 0, stream>>>((const unsigned*)s0a, flag);
  cvt_k<<<(WTOT + 255) / 256, 256, 0, stream>>>(w0a, w0b, wd0, w1a, w1b,
                                                s0a, b0a, s0b, b0b, sd0, bd0,
                                                s1a, b1a, s1b, b1b, flag, wbuf);
  masklist_k<<<N3 / 256, 256, 0, stream>>>(mask, list, cnt);
  dsmask_k<<<M3 / 256, 256, 0, stream>>>(mask, m1);

  if (fp32path) {
    float* h0 = (float*)(ws + o_A);
    float* h1 = (float*)(ws + o_B);
    conv0a_k<float><<<N3 / 256, 256, 0, stream>>>(xf, flag, mask, list, cnt, wbuf, h0);
    conv0b_k<float><<<N3 / 256, 256, 0, stream>>>(h0, list, cnt, wbuf, h1);
    convd0_k<float><<<M3 / 256, 256, 0, stream>>>(h1, m1, wbuf, hd);
  } else {
    __hip_bfloat16* h0 = (__hip_bfloat16*)(ws + o_A);
    __hip_bfloat16* h1 = (__hip_bfloat16*)(ws + o_B);
    conv0a_k<__hip_bfloat16><<<N3 / 256, 256, 0, stream>>>(xf, flag, mask, list, cnt, wbuf, h0);
    conv0b_k<__hip_bfloat16><<<N3 / 256, 256, 0, stream>>>(h0, list, cnt, wbuf, h1);
    convd0_k<__hip_bfloat16><<<M3 / 256, 256, 0, stream>>>(h1, m1, wbuf, hd);
  }
  conv1_k<<<M3 / 256, 256, 0, stream>>>(hd, m1, wbuf, OW1A, OS1A, OB1A, h2);
  conv1_k<<<M3 / 256, 256, 0, stream>>>(h2, m1, wbuf, OW1B, OS1B, OB1B, h3);
  sample_k<<<NPTS / 256, 256, 0, stream>>>(coords, flag, h3, d_out);
}

// Round 3
// 1265.510 us; speedup vs baseline: 1.6742x; 1.6742x over previous
//
#include <hip/hip_runtime.h>
#include <hip/hip_bf16.h>

#define N   128
#define N3  (N*N*N)
#define M   64
#define M3  (M*M*M)
#define NPTS 65536
#define PD  66
#define PD2 (PD*PD)
#define PVOX (PD*PD*PD)

// float offsets inside the converted-weights buffer
enum : int {
  OW0A = 0,                 // 16*3*27   = 1296
  OW0B = 1296,              // 16*16*27  = 6912
  OWD0 = 8208,              // 32*16*27  = 13824
  OW1A = 22032,             // 32*32*27  = 27648
  OW1B = 49680,             // 32*32*27  = 27648
  OS0A = 77328, OB0A = 77344,
  OS0B = 77360, OB0B = 77376,
  OSD0 = 77392, OBD0 = 77424,
  OS1A = 77456, OB1A = 77488,
  OS1B = 77520, OB1B = 77552,
  WTOT = 77584
};

typedef short bf16x8 __attribute__((ext_vector_type(8)));
typedef float f32x4  __attribute__((ext_vector_type(4)));

__device__ __forceinline__ float ldT(const __hip_bfloat16* p) { return __bfloat162float(*p); }
__device__ __forceinline__ void stT(__hip_bfloat16* p, float v) { *p = __float2bfloat16(v); }

__device__ __forceinline__ unsigned short f2bf_bits(float f) {
  __hip_bfloat16 b = __float2bfloat16(f);
  union { __hip_bfloat16 b; unsigned short u; } cv; cv.b = b; return cv.u;
}
__device__ __forceinline__ float bfbits2f(short s) {
  union { unsigned u; float f; } c; c.u = ((unsigned)(unsigned short)s) << 16; return c.f;
}

// read element i of an input whose dtype is decided at runtime (bf=1 -> bf16)
__device__ __forceinline__ float ldIn(const void* p, long i, int bf) {
  return bf ? __bfloat162float(((const __hip_bfloat16*)p)[i]) : ((const float*)p)[i];
}

// ---- dtype probe: s0a ~ uniform(0.5,1.5). bf16-packed => byte1 of every word is 0x3F.
__global__ void probe_k(const unsigned* __restrict__ s0a_raw, int* __restrict__ flag) {
  if (threadIdx.x == 0 && blockIdx.x == 0) {
    int all = 1;
    for (int i = 0; i < 8; ++i) {
      unsigned w = s0a_raw[i];
      if (((w >> 8) & 0xFFu) != 0x3Fu) all = 0;
    }
    *flag = all;
  }
}

// ---- convert all weights/scales/shifts (either dtype) to one fp32 buffer ----
__global__ __launch_bounds__(256) void cvt_k(
    const void* w0a, const void* w0b, const void* wd0,
    const void* w1a, const void* w1b,
    const void* s0a, const void* b0a,
    const void* s0b, const void* b0b,
    const void* sd0, const void* bd0,
    const void* s1a, const void* b1a,
    const void* s1b, const void* b1b,
    const int* __restrict__ flag, float* __restrict__ wbuf)
{
  int i = blockIdx.x * 256 + threadIdx.x;
  if (i >= WTOT) return;
  int bf = *flag;
  const void* src; int off;
  if      (i < OW0B) { src = w0a; off = OW0A; }
  else if (i < OWD0) { src = w0b; off = OW0B; }
  else if (i < OW1A) { src = wd0; off = OWD0; }
  else if (i < OW1B) { src = w1a; off = OW1A; }
  else if (i < OS0A) { src = w1b; off = OW1B; }
  else if (i < OB0A) { src = s0a; off = OS0A; }
  else if (i < OS0B) { src = b0a; off = OB0A; }
  else if (i < OB0B) { src = s0b; off = OS0B; }
  else if (i < OSD0) { src = b0b; off = OB0B; }
  else if (i < OBD0) { src = sd0; off = OSD0; }
  else if (i < OS1A) { src = bd0; off = OBD0; }
  else if (i < OB1A) { src = s1a; off = OS1A; }
  else if (i < OS1B) { src = b1a; off = OB1A; }
  else if (i < OB1B) { src = s1b; off = OS1B; }
  else               { src = b1b; off = OB1B; }
  wbuf[i] = ldIn(src, i - off, bf);
}

// ---- active-voxel list from mask ----
__global__ __launch_bounds__(256) void masklist_k(const int* __restrict__ mask,
                                                  int* __restrict__ list,
                                                  int* __restrict__ cnt)
{
  int idx = blockIdx.x * 256 + threadIdx.x;
  if (idx >= N3) return;
  if (mask[idx]) { int p = atomicAdd(cnt, 1); list[p] = idx; }
}

// ---- m1f = float(maxpool3d(mask, 3, stride 2, pad 1)) ----
__global__ __launch_bounds__(256) void dsmask_k(const int* __restrict__ mask,
                                                float* __restrict__ m1f)
{
  int idx = blockIdx.x * 256 + threadIdx.x;
  if (idx >= M3) return;
  int z = idx >> 12, y = (idx >> 6) & 63, x = idx & 63;
  int r = 0;
  #pragma unroll
  for (int dz = 0; dz < 3; ++dz) {
    int iz = 2 * z + dz - 1;
    if ((unsigned)iz >= 128u) continue;
    #pragma unroll
    for (int dy = 0; dy < 3; ++dy) {
      int iy = 2 * y + dy - 1;
      if ((unsigned)iy >= 128u) continue;
      #pragma unroll
      for (int dx = 0; dx < 3; ++dx) {
        int ix = 2 * x + dx - 1;
        if ((unsigned)ix >= 128u) continue;
        r |= mask[(iz << 14) | (iy << 7) | ix];
      }
    }
  }
  m1f[idx] = r ? 1.f : 0.f;
}

// ---- conv0a: 3->16 at active voxels only ----
__global__ __launch_bounds__(256) void conv0a_k(
    const void* __restrict__ xf, const int* __restrict__ flag,
    const int* __restrict__ mask,
    const int* __restrict__ list, const int* __restrict__ cnt,
    const float* __restrict__ wbuf, __hip_bfloat16* __restrict__ h0)
{
  int i = blockIdx.x * 256 + threadIdx.x;
  if (i >= *cnt) return;
  int bf = *flag;
  int idx = list[i];
  int z = idx >> 14, y = (idx >> 7) & 127, x = idx & 127;
  float v[3][27];
  #pragma unroll
  for (int dz = 0; dz < 3; ++dz)
  #pragma unroll
  for (int dy = 0; dy < 3; ++dy)
  #pragma unroll
  for (int dx = 0; dx < 3; ++dx) {
    int k = dz * 9 + dy * 3 + dx;
    int iz = z + dz - 1, iy = y + dy - 1, ix = x + dx - 1;
    bool ok = (unsigned)iz < 128u && (unsigned)iy < 128u && (unsigned)ix < 128u;
    int t = ok ? ((iz << 14) | (iy << 7) | ix) : 0;
    bool act = ok && (mask[t] != 0);
    v[0][k] = act ? ldIn(xf, t, bf) : 0.f;
    v[1][k] = act ? ldIn(xf, (long)N3 + t, bf) : 0.f;
    v[2][k] = act ? ldIn(xf, 2l * N3 + t, bf) : 0.f;
  }
  #pragma unroll
  for (int oc = 0; oc < 16; ++oc) {
    float acc = 0.f;
    #pragma unroll
    for (int ic = 0; ic < 3; ++ic) {
      const float* w = wbuf + OW0A + (oc * 3 + ic) * 27;
      #pragma unroll
      for (int k = 0; k < 27; ++k) acc = fmaf(w[k], v[ic][k], acc);
    }
    float r = fmaxf(fmaf(acc, wbuf[OS0A + oc], wbuf[OB0A + oc]), 0.f);
    stT(h0 + (size_t)oc * N3 + idx, r);
  }
}

// ---- conv0b: 16->16 at active voxels only ----
__global__ __launch_bounds__(256) void conv0b_k(
    const __hip_bfloat16* __restrict__ h0, const int* __restrict__ list,
    const int* __restrict__ cnt,
    const float* __restrict__ wbuf, __hip_bfloat16* __restrict__ h1)
{
  int i = blockIdx.x * 256 + threadIdx.x;
  if (i >= *cnt) return;
  int idx = list[i];
  int z = idx >> 14, y = (idx >> 7) & 127, x = idx & 127;
  int toff[27]; bool tv[27];
  #pragma unroll
  for (int dz = 0; dz < 3; ++dz)
  #pragma unroll
  for (int dy = 0; dy < 3; ++dy)
  #pragma unroll
  for (int dx = 0; dx < 3; ++dx) {
    int k = dz * 9 + dy * 3 + dx;
    int iz = z + dz - 1, iy = y + dy - 1, ix = x + dx - 1;
    bool ok = (unsigned)iz < 128u && (unsigned)iy < 128u && (unsigned)ix < 128u;
    tv[k] = ok;
    toff[k] = ok ? ((iz << 14) | (iy << 7) | ix) : 0;
  }
  float acc[16];
  #pragma unroll
  for (int oc = 0; oc < 16; ++oc) acc[oc] = 0.f;
  for (int ic = 0; ic < 16; ++ic) {
    float t[27];
    #pragma unroll
    for (int k = 0; k < 27; ++k) t[k] = tv[k] ? ldT(h0 + (size_t)ic * N3 + toff[k]) : 0.f;
    #pragma unroll
    for (int oc = 0; oc < 16; ++oc) {
      const float* w = wbuf + OW0B + (oc * 16 + ic) * 27;
      #pragma unroll
      for (int k = 0; k < 27; ++k) acc[oc] = fmaf(w[k], t[k], acc[oc]);
    }
  }
  #pragma unroll
  for (int oc = 0; oc < 16; ++oc) {
    float r = fmaxf(fmaf(acc[oc], wbuf[OS0B + oc], wbuf[OB0B + oc]), 0.f);
    stT(h1 + (size_t)oc * N3 + idx, r);
  }
}

// ---- convd0: 16->32, stride 2; writes channel-last padded bf16 volume P1 ----
__global__ __launch_bounds__(256) void convd0_k(
    const __hip_bfloat16* __restrict__ h1, const float* __restrict__ m1f,
    const float* __restrict__ wbuf, short* __restrict__ P1)
{
  int idx = blockIdx.x * 256 + threadIdx.x;
  if (idx >= M3) return;
  int z = idx >> 12, y = (idx >> 6) & 63, x = idx & 63;
  int pvox = ((z + 1) * PD + (y + 1)) * PD + (x + 1);
  uint4* dst = (uint4*)(P1 + (size_t)pvox * 32);
  if (m1f[idx] == 0.f) {
    uint4 zz = {0u, 0u, 0u, 0u};
    dst[0] = zz; dst[1] = zz; dst[2] = zz; dst[3] = zz;
    return;
  }
  int toff[27]; bool tv[27];
  #pragma unroll
  for (int dz = 0; dz < 3; ++dz)
  #pragma unroll
  for (int dy = 0; dy < 3; ++dy)
  #pragma unroll
  for (int dx = 0; dx < 3; ++dx) {
    int k = dz * 9 + dy * 3 + dx;
    int iz = 2 * z + dz - 1, iy = 2 * y + dy - 1, ix = 2 * x + dx - 1;
    bool ok = (unsigned)iz < 128u && (unsigned)iy < 128u && (unsigned)ix < 128u;
    tv[k] = ok;
    toff[k] = ok ? ((iz << 14) | (iy << 7) | ix) : 0;
  }
  float acc[32];
  #pragma unroll
  for (int oc = 0; oc < 32; ++oc) acc[oc] = 0.f;
  for (int ic = 0; ic < 16; ++ic) {
    float t[27];
    #pragma unroll
    for (int k = 0; k < 27; ++k) t[k] = tv[k] ? ldT(h1 + (size_t)ic * N3 + toff[k]) : 0.f;
    #pragma unroll
    for (int oc = 0; oc < 32; ++oc) {
      const float* w = wbuf + OWD0 + (oc * 16 + ic) * 27;
      #pragma unroll
      for (int k = 0; k < 27; ++k) acc[oc] = fmaf(w[k], t[k], acc[oc]);
    }
  }
  #pragma unroll
  for (int g = 0; g < 4; ++g) {
    union { unsigned short us[8]; uint4 v; } u;
    #pragma unroll
    for (int j = 0; j < 8; ++j) {
      int oc = g * 8 + j;
      float r = fmaxf(fmaf(acc[oc], wbuf[OSD0 + oc], wbuf[OBD0 + oc]), 0.f);
      u.us[j] = f2bf_bits(r);
    }
    dst[g] = u.v;
  }
}

// ---- conv1 via MFMA implicit GEMM: 32->32 ch over padded 66^3 channel-last bf16 ----
// wave handles 2 (y,z)-rows x 4 x-tiles = 128 voxels x 32 oc.
__global__ __launch_bounds__(256) void conv1_mfma_k(
    const short* __restrict__ Pin, short* __restrict__ Pout,
    const float* __restrict__ wbuf, int wof, int sof, int bof,
    const float* __restrict__ m1f)
{
  __shared__ short ldsB[27 * 2 * 64 * 8];   // 54 KB: B-frags [tap][ochalf][lane][j]
  int tid = threadIdx.x;
  for (int e = tid; e < 27 * 1024; e += 256) {
    int t = e >> 10;
    int h = (e >> 9) & 1;
    int l = (e >> 3) & 63;
    int j = e & 7;
    int ic = ((l >> 4) << 3) + j;          // B[k=ic]
    int oc = (h << 4) + (l & 15);          // B[n=oc]
    ldsB[e] = (short)f2bf_bits(wbuf[wof + (oc * 32 + ic) * 27 + t]);
  }
  __syncthreads();

  int wave = tid >> 6, lane = tid & 63;
  int quad = lane >> 4, l15 = lane & 15;

  f32x4 acc[2][4][2];
  #pragma unroll
  for (int rr = 0; rr < 2; ++rr)
  #pragma unroll
  for (int tt = 0; tt < 4; ++tt)
  #pragma unroll
  for (int h = 0; h < 2; ++h) {
    f32x4 zf = {0.f, 0.f, 0.f, 0.f};
    acc[rr][tt][h] = zf;
  }

  int rowid0 = blockIdx.x * 8 + wave * 2;
  int abase[2], zz[2], yy[2];
  #pragma unroll
  for (int rr = 0; rr < 2; ++rr) {
    int rowid = rowid0 + rr;
    zz[rr] = rowid >> 6; yy[rr] = rowid & 63;
    abase[rr] = ((zz[rr] + 1) * PD + (yy[rr] + 1)) * PD + 1;   // interior x=0 voxel
  }

  #pragma unroll 1
  for (int k = 0; k < 27; ++k) {
    int dz = k / 9, r9 = k - dz * 9, dy = r9 / 3, dx = r9 - dy * 3;
    int shift = (dz - 1) * PD2 + (dy - 1) * PD + (dx - 1);
    bf16x8 b0 = *(const bf16x8*)&ldsB[((k * 2 + 0) * 64 + lane) * 8];
    bf16x8 b1 = *(const bf16x8*)&ldsB[((k * 2 + 1) * 64 + lane) * 8];
    bf16x8 a[2][4];
    #pragma unroll
    for (int rr = 0; rr < 2; ++rr)
    #pragma unroll
    for (int tt = 0; tt < 4; ++tt) {
      int off = (abase[rr] + shift + tt * 16 + l15) * 32 + quad * 8;
      a[rr][tt] = *(const bf16x8*)(Pin + off);
    }
    #pragma unroll
    for (int rr = 0; rr < 2; ++rr)
    #pragma unroll
    for (int tt = 0; tt < 4; ++tt) {
      acc[rr][tt][0] = __builtin_amdgcn_mfma_f32_16x16x32_bf16(a[rr][tt], b0, acc[rr][tt][0], 0, 0, 0);
      acc[rr][tt][1] = __builtin_amdgcn_mfma_f32_16x16x32_bf16(a[rr][tt], b1, acc[rr][tt][1], 0, 0, 0);
    }
  }

  float sc[2] = { wbuf[sof + l15], wbuf[sof + 16 + l15] };
  float sh[2] = { wbuf[bof + l15], wbuf[bof + 16 + l15] };

  #pragma unroll
  for (int rr = 0; rr < 2; ++rr) {
    int mrow = (zz[rr] * 64 + yy[rr]) * 64;
    #pragma unroll
    for (int tt = 0; tt < 4; ++tt) {
      const float4 mv = *(const float4*)&m1f[mrow + tt * 16 + quad * 4];
      float mvr[4] = {mv.x, mv.y, mv.z, mv.w};
      #pragma unroll
      for (int h = 0; h < 2; ++h) {
        #pragma unroll
        for (int r = 0; r < 4; ++r) {
          float v = fmaxf(fmaf(acc[rr][tt][h][r], sc[h], sh[h]), 0.f) * mvr[r];
          int vox = abase[rr] + tt * 16 + quad * 4 + r;
          Pout[vox * 32 + h * 16 + l15] = (short)f2bf_bits(v);
        }
      }
    }
  }
}

// ---- trilinear sample from padded channel-last bf16 volume ----
__global__ __launch_bounds__(256) void sample_k(
    const void* __restrict__ coords, const int* __restrict__ flag,
    const short* __restrict__ vol, void* __restrict__ out)
{
  int p = blockIdx.x * 256 + threadIdx.x;
  if (p >= NPTS) return;
  int bf = *flag;
  float cx = ldIn(coords, 3l * p + 0, bf);
  float cy = ldIn(coords, 3l * p + 1, bf);
  float cz = ldIn(coords, 3l * p + 2, bf);
  float fx = (cx + 1.f) * 0.5f * 63.f;
  float fy = (cy + 1.f) * 0.5f * 63.f;
  float fz = (cz + 1.f) * 0.5f * 63.f;
  float x0f = floorf(fx), y0f = floorf(fy), z0f = floorf(fz);
  int x0 = (int)x0f, y0 = (int)y0f, z0 = (int)z0f;
  float tx = fx - x0f, ty = fy - y0f, tz = fz - z0f;
  int li[8]; float wt[8];
  #pragma unroll
  for (int dz = 0; dz < 2; ++dz)
  #pragma unroll
  for (int dy = 0; dy < 2; ++dy)
  #pragma unroll
  for (int dx = 0; dx < 2; ++dx) {
    int t = dz * 4 + dy * 2 + dx;
    int xi = x0 + dx, yi = y0 + dy, zi = z0 + dz;
    bool ok = (unsigned)xi < 64u && (unsigned)yi < 64u && (unsigned)zi < 64u;
    int xc = min(max(xi, 0), 63), yc = min(max(yi, 0), 63), zc = min(max(zi, 0), 63);
    li[t] = ((zc + 1) * PD + (yc + 1)) * PD + (xc + 1);
    float w = (dx ? tx : 1.f - tx) * (dy ? ty : 1.f - ty) * (dz ? tz : 1.f - tz);
    wt[t] = ok ? w : 0.f;
  }
  #pragma unroll
  for (int cc = 0; cc < 4; ++cc) {
    float s[8];
    #pragma unroll
    for (int j = 0; j < 8; ++j) s[j] = 0.f;
    #pragma unroll
    for (int t = 0; t < 8; ++t) {
      bf16x8 v = *(const bf16x8*)(vol + (size_t)li[t] * 32 + cc * 8);
      #pragma unroll
      for (int j = 0; j < 8; ++j) s[j] += bfbits2f(v[j]) * wt[t];
    }
    if (bf) {
      union { unsigned short us[8]; uint4 v; } u;
      #pragma unroll
      for (int j = 0; j < 8; ++j) u.us[j] = f2bf_bits(s[j]);
      ((uint4*)out)[p * 4 + cc] = u.v;
    } else {
      #pragma unroll
      for (int j = 0; j < 8; ++j) ((float*)out)[(size_t)p * 32 + cc * 8 + j] = s[j];
    }
  }
}

extern "C" void kernel_launch(void* const* d_in, const int* in_sizes, int n_in,
                              void* d_out, int out_size, void* d_ws, size_t ws_size,
                              hipStream_t stream)
{
  const void* xf     = d_in[0];
  const int*  mask   = (const int*)d_in[1];
  const void* coords = d_in[2];
  const void* w0a = d_in[3];
  const void* s0a = d_in[4];
  const void* b0a = d_in[5];
  const void* w0b = d_in[6];
  const void* s0b = d_in[7];
  const void* b0b = d_in[8];
  const void* wd0 = d_in[9];
  const void* sd0 = d_in[10];
  const void* bd0 = d_in[11];
  const void* w1a = d_in[12];
  const void* s1a = d_in[13];
  const void* b1a = d_in[14];
  const void* w1b = d_in[15];
  const void* s1b = d_in[16];
  const void* b1b = d_in[17];

  char* ws = (char*)d_ws;
  size_t cur = 0;
  auto alloc = [&](size_t bytes) -> size_t {
    size_t o = cur; cur = (cur + bytes + 255) & ~(size_t)255; return o;
  };
  size_t o_flag = alloc(4);
  size_t o_cnt  = alloc(4);
  size_t o_m1f  = alloc((size_t)M3 * 4);
  size_t o_wbuf = alloc((size_t)WTOT * 4);
  size_t o_list = alloc((size_t)N3 * 4);
  size_t o_P1   = alloc((size_t)PVOX * 32 * 2);   // padded channel-last bf16
  size_t o_P2   = alloc((size_t)PVOX * 32 * 2);
  size_t o_h0   = alloc((size_t)16 * N3 * 2);     // bf16 channel-major
  size_t o_h1   = alloc((size_t)16 * N3 * 2);

  int*   flag = (int*)(ws + o_flag);
  int*   cnt  = (int*)(ws + o_cnt);
  float* m1f  = (float*)(ws + o_m1f);
  float* wbuf = (float*)(ws + o_wbuf);
  int*   list = (int*)(ws + o_list);
  short* P1   = (short*)(ws + o_P1);
  short* P2   = (short*)(ws + o_P2);
  __hip_bfloat16* h0 = (__hip_bfloat16*)(ws + o_h0);
  __hip_bfloat16* h1 = (__hip_bfloat16*)(ws + o_h1);

  hipMemsetAsync(cnt, 0, 4, stream);
  hipMemsetAsync(ws + o_P1, 0, 2ull * PVOX * 32 * 2, stream);   // P1+P2 contiguous
  hipMemsetAsync(ws + o_h0, 0, 2ull * 16 * N3 * 2, stream);     // h0+h1 contiguous

  probe_k<<<1, 64, 0, stream>>>((const unsigned*)s0a, flag);
  cvt_k<<<(WTOT + 255) / 256, 256, 0, stream>>>(w0a, w0b, wd0, w1a, w1b,
                                                s0a, b0a, s0b, b0b, sd0, bd0,
                                                s1a, b1a, s1b, b1b, flag, wbuf);
  masklist_k<<<N3 / 256, 256, 0, stream>>>(mask, list, cnt);
  dsmask_k<<<M3 / 256, 256, 0, stream>>>(mask, m1f);

  conv0a_k<<<N3 / 256, 256, 0, stream>>>(xf, flag, mask, list, cnt, wbuf, h0);
  conv0b_k<<<N3 / 256, 256, 0, stream>>>(h0, list, cnt, wbuf, h1);
  convd0_k<<<M3 / 256, 256, 0, stream>>>(h1, m1f, wbuf, P1);

  conv1_mfma_k<<<512, 256, 0, stream>>>(P1, P2, wbuf, OW1A, OS1A, OB1A, m1f);
  conv1_mfma_k<<<512, 256, 0, stream>>>(P2, P1, wbuf, OW1B, OS1B, OB1B, m1f);

  sample_k<<<NPTS / 256, 256, 0, stream>>>(coords, flag, P1, d_out);
}

// Round 4
// 552.744 us; speedup vs baseline: 3.8331x; 2.2895x over previous
//
#include <hip/hip_runtime.h>
#include <hip/hip_bf16.h>

#define N   128
#define N3  (N*N*N)
#define M   64
#define M3  (M*M*M)
#define NPTS 65536
#define PD  66
#define PD2 (PD*PD)
#define PVOX (PD*PD*PD)
#define PH  130
#define PH2 (PH*PH)
#define PH3 (PH*PH*PH)

// float offsets inside the converted-weights buffer
enum : int {
  OW0A = 0,                 // 16*3*27   = 1296
  OW0B = 1296,              // 16*16*27  = 6912
  OWD0 = 8208,              // 32*16*27  = 13824
  OW1A = 22032,             // 32*32*27  = 27648
  OW1B = 49680,             // 32*32*27  = 27648
  OS0A = 77328, OB0A = 77344,
  OS0B = 77360, OB0B = 77376,
  OSD0 = 77392, OBD0 = 77424,
  OS1A = 77456, OB1A = 77488,
  OS1B = 77520, OB1B = 77552,
  WTOT = 77584
};

typedef short bf16x8 __attribute__((ext_vector_type(8)));
typedef float f32x4  __attribute__((ext_vector_type(4)));

__device__ __forceinline__ unsigned short f2bf_bits(float f) {
  __hip_bfloat16 b = __float2bfloat16(f);
  union { __hip_bfloat16 b; unsigned short u; } cv; cv.b = b; return cv.u;
}
__device__ __forceinline__ float bfbits2f(short s) {
  union { unsigned u; float f; } c; c.u = ((unsigned)(unsigned short)s) << 16; return c.f;
}

// read element i of an input whose dtype is decided at runtime (bf=1 -> bf16)
__device__ __forceinline__ float ldIn(const void* p, long i, int bf) {
  return bf ? __bfloat162float(((const __hip_bfloat16*)p)[i]) : ((const float*)p)[i];
}

// ---- dtype probe: s0a ~ uniform(0.5,1.5). bf16-packed => byte1 of every word is 0x3F.
__global__ void probe_k(const unsigned* __restrict__ s0a_raw, int* __restrict__ flag) {
  if (threadIdx.x == 0 && blockIdx.x == 0) {
    int all = 1;
    for (int i = 0; i < 8; ++i) {
      unsigned w = s0a_raw[i];
      if (((w >> 8) & 0xFFu) != 0x3Fu) all = 0;
    }
    *flag = all;
  }
}

// ---- convert all weights/scales/shifts (either dtype) to one fp32 buffer ----
__global__ __launch_bounds__(256) void cvt_k(
    const void* w0a, const void* w0b, const void* wd0,
    const void* w1a, const void* w1b,
    const void* s0a, const void* b0a,
    const void* s0b, const void* b0b,
    const void* sd0, const void* bd0,
    const void* s1a, const void* b1a,
    const void* s1b, const void* b1b,
    const int* __restrict__ flag, float* __restrict__ wbuf)
{
  int i = blockIdx.x * 256 + threadIdx.x;
  if (i >= WTOT) return;
  int bf = *flag;
  const void* src; int off;
  if      (i < OW0B) { src = w0a; off = OW0A; }
  else if (i < OWD0) { src = w0b; off = OW0B; }
  else if (i < OW1A) { src = wd0; off = OWD0; }
  else if (i < OW1B) { src = w1a; off = OW1A; }
  else if (i < OS0A) { src = w1b; off = OW1B; }
  else if (i < OB0A) { src = s0a; off = OS0A; }
  else if (i < OS0B) { src = b0a; off = OB0A; }
  else if (i < OB0B) { src = s0b; off = OS0B; }
  else if (i < OSD0) { src = b0b; off = OB0B; }
  else if (i < OBD0) { src = sd0; off = OSD0; }
  else if (i < OS1A) { src = bd0; off = OBD0; }
  else if (i < OB1A) { src = s1a; off = OS1A; }
  else if (i < OS1B) { src = b1a; off = OB1A; }
  else if (i < OB1B) { src = s1b; off = OS1B; }
  else               { src = b1b; off = OB1B; }
  wbuf[i] = ldIn(src, i - off, bf);
}

// ---- transpose conv0b/convd0 weights to [tap][ic][oc] for uniform contiguous reads ----
__global__ __launch_bounds__(256) void wtrans_k(const float* __restrict__ wbuf,
                                               float* __restrict__ T0B,
                                               float* __restrict__ TD0)
{
  int i = blockIdx.x * 256 + threadIdx.x;
  if (i < 27 * 256) {
    int k = i >> 8, r = i & 255, ic = r >> 4, oc = r & 15;
    T0B[i] = wbuf[OW0B + (oc * 16 + ic) * 27 + k];
  }
  if (i < 27 * 512) {
    int k = i / 512, r = i % 512, ic = r >> 5, oc = r & 31;
    TD0[i] = wbuf[OWD0 + (oc * 16 + ic) * 27 + k];
  }
}

// ---- active-voxel list: block-aggregated, ONE global atomic per block ----
__global__ __launch_bounds__(256) void masklist_k(const int* __restrict__ mask,
                                                  int* __restrict__ list,
                                                  int* __restrict__ cnt)
{
  __shared__ int lpos, lbase;
  int t = threadIdx.x;
  int start = blockIdx.x * 8192;        // 256 blocks x 8192 voxels = N3
  if (t == 0) lpos = 0;
  __syncthreads();
  int myc = 0;
  #pragma unroll 4
  for (int i = 0; i < 32; ++i) myc += (mask[start + i * 256 + t] != 0);
  atomicAdd(&lpos, myc);
  __syncthreads();
  if (t == 0) { lbase = atomicAdd(cnt, lpos); lpos = 0; }
  __syncthreads();
  #pragma unroll 4
  for (int i = 0; i < 32; ++i) {
    int idx = start + i * 256 + t;
    if (mask[idx]) {
      int p = atomicAdd(&lpos, 1);
      list[lbase + p] = idx;
    }
  }
}

// ---- m1f = float(maxpool3d(mask, 3, stride 2, pad 1)) ----
__global__ __launch_bounds__(256) void dsmask_k(const int* __restrict__ mask,
                                                float* __restrict__ m1f)
{
  int idx = blockIdx.x * 256 + threadIdx.x;
  if (idx >= M3) return;
  int z = idx >> 12, y = (idx >> 6) & 63, x = idx & 63;
  int r = 0;
  #pragma unroll
  for (int dz = 0; dz < 3; ++dz) {
    int iz = 2 * z + dz - 1;
    if ((unsigned)iz >= 128u) continue;
    #pragma unroll
    for (int dy = 0; dy < 3; ++dy) {
      int iy = 2 * y + dy - 1;
      if ((unsigned)iy >= 128u) continue;
      #pragma unroll
      for (int dx = 0; dx < 3; ++dx) {
        int ix = 2 * x + dx - 1;
        if ((unsigned)ix >= 128u) continue;
        r |= mask[(iz << 14) | (iy << 7) | ix];
      }
    }
  }
  m1f[idx] = r ? 1.f : 0.f;
}

// ---- conv0a: 3->16 at active voxels; writes channel-last padded 130^3 bf16 ----
__global__ __launch_bounds__(256) void conv0a_k(
    const void* __restrict__ xf, const int* __restrict__ flag,
    const int* __restrict__ mask,
    const int* __restrict__ list, const int* __restrict__ cnt,
    const float* __restrict__ wbuf, short* __restrict__ h0p)
{
  int nact = *cnt;
  int bf = *flag;
  for (int i = blockIdx.x * 256 + threadIdx.x; i < nact; i += 2048 * 256) {
    int idx = list[i];
    int z = idx >> 14, y = (idx >> 7) & 127, x = idx & 127;
    float v[3][27];
    #pragma unroll
    for (int dz = 0; dz < 3; ++dz)
    #pragma unroll
    for (int dy = 0; dy < 3; ++dy)
    #pragma unroll
    for (int dx = 0; dx < 3; ++dx) {
      int k = dz * 9 + dy * 3 + dx;
      int iz = z + dz - 1, iy = y + dy - 1, ix = x + dx - 1;
      bool ok = (unsigned)iz < 128u && (unsigned)iy < 128u && (unsigned)ix < 128u;
      int t = ok ? ((iz << 14) | (iy << 7) | ix) : 0;
      bool act = ok && (mask[t] != 0);
      v[0][k] = act ? ldIn(xf, t, bf) : 0.f;
      v[1][k] = act ? ldIn(xf, (long)N3 + t, bf) : 0.f;
      v[2][k] = act ? ldIn(xf, 2l * N3 + t, bf) : 0.f;
    }
    int pv = ((z + 1) * PH + (y + 1)) * PH + (x + 1);
    uint4* dst = (uint4*)(h0p + (size_t)pv * 16);
    #pragma unroll
    for (int g = 0; g < 2; ++g) {
      union { unsigned short us[8]; uint4 v; } u;
      #pragma unroll
      for (int j = 0; j < 8; ++j) {
        int oc = g * 8 + j;
        float acc = 0.f;
        #pragma unroll
        for (int ic = 0; ic < 3; ++ic) {
          const float* w = wbuf + OW0A + (oc * 3 + ic) * 27;
          #pragma unroll
          for (int k = 0; k < 27; ++k) acc = fmaf(w[k], v[ic][k], acc);
        }
        u.us[j] = f2bf_bits(fmaxf(fmaf(acc, wbuf[OS0A + oc], wbuf[OB0A + oc]), 0.f));
      }
      dst[g] = u.v;
    }
  }
}

// ---- conv0b: 16->16 at active voxels, channel-last in/out ----
__global__ __launch_bounds__(256) void conv0b_k(
    const short* __restrict__ h0p, const int* __restrict__ list,
    const int* __restrict__ cnt,
    const float* __restrict__ T0B, const float* __restrict__ wbuf,
    short* __restrict__ h1p)
{
  int nact = *cnt;
  for (int i = blockIdx.x * 256 + threadIdx.x; i < nact; i += 2048 * 256) {
    int idx = list[i];
    int z = idx >> 14, y = (idx >> 7) & 127, x = idx & 127;
    int pv = ((z + 1) * PH + (y + 1)) * PH + (x + 1);
    float acc[16];
    #pragma unroll
    for (int oc = 0; oc < 16; ++oc) acc[oc] = 0.f;
    #pragma unroll 3
    for (int k = 0; k < 27; ++k) {
      int dz = k / 9, r9 = k - dz * 9, dy = r9 / 3, dx = r9 - dy * 3;
      int nb = pv + (dz - 1) * PH2 + (dy - 1) * PH + (dx - 1);
      const short* np = h0p + (size_t)nb * 16;
      bf16x8 v0 = *(const bf16x8*)np;
      bf16x8 v1 = *(const bf16x8*)(np + 8);
      float f[16];
      #pragma unroll
      for (int j = 0; j < 8; ++j) { f[j] = bfbits2f(v0[j]); f[8 + j] = bfbits2f(v1[j]); }
      const float* w = T0B + k * 256;
      #pragma unroll
      for (int ic = 0; ic < 16; ++ic)
        #pragma unroll
        for (int oc = 0; oc < 16; ++oc)
          acc[oc] = fmaf(w[ic * 16 + oc], f[ic], acc[oc]);
    }
    uint4* dst = (uint4*)(h1p + (size_t)pv * 16);
    #pragma unroll
    for (int g = 0; g < 2; ++g) {
      union { unsigned short us[8]; uint4 v; } u;
      #pragma unroll
      for (int j = 0; j < 8; ++j) {
        int oc = g * 8 + j;
        u.us[j] = f2bf_bits(fmaxf(fmaf(acc[oc], wbuf[OS0B + oc], wbuf[OB0B + oc]), 0.f));
      }
      dst[g] = u.v;
    }
  }
}

// ---- convd0: 16->32, stride 2; channel-last in (130^3), out padded 66^3 ----
__global__ __launch_bounds__(256) void convd0_k(
    const short* __restrict__ h1p, const float* __restrict__ m1f,
    const float* __restrict__ TD0, const float* __restrict__ wbuf,
    short* __restrict__ P1)
{
  int idx = blockIdx.x * 256 + threadIdx.x;
  if (idx >= M3) return;
  int z = idx >> 12, y = (idx >> 6) & 63, x = idx & 63;
  int pvo = ((z + 1) * PD + (y + 1)) * PD + (x + 1);
  uint4* dst = (uint4*)(P1 + (size_t)pvo * 32);
  if (m1f[idx] == 0.f) {
    uint4 zz = {0u, 0u, 0u, 0u};
    dst[0] = zz; dst[1] = zz; dst[2] = zz; dst[3] = zz;
    return;
  }
  int base_in = ((2 * z) * PH + 2 * y) * PH + 2 * x;   // padded idx of (2z-1,2y-1,2x-1)+1
  float acc[32];
  #pragma unroll
  for (int oc = 0; oc < 32; ++oc) acc[oc] = 0.f;
  #pragma unroll 3
  for (int k = 0; k < 27; ++k) {
    int dz = k / 9, r9 = k - dz * 9, dy = r9 / 3, dx = r9 - dy * 3;
    int nb = base_in + dz * PH2 + dy * PH + dx;
    const short* np = h1p + (size_t)nb * 16;
    bf16x8 v0 = *(const bf16x8*)np;
    bf16x8 v1 = *(const bf16x8*)(np + 8);
    float f[16];
    #pragma unroll
    for (int j = 0; j < 8; ++j) { f[j] = bfbits2f(v0[j]); f[8 + j] = bfbits2f(v1[j]); }
    const float* w = TD0 + k * 512;
    #pragma unroll
    for (int ic = 0; ic < 16; ++ic)
      #pragma unroll
      for (int oc = 0; oc < 32; ++oc)
        acc[oc] = fmaf(w[ic * 32 + oc], f[ic], acc[oc]);
  }
  #pragma unroll
  for (int g = 0; g < 4; ++g) {
    union { unsigned short us[8]; uint4 v; } u;
    #pragma unroll
    for (int j = 0; j < 8; ++j) {
      int oc = g * 8 + j;
      u.us[j] = f2bf_bits(fmaxf(fmaf(acc[oc], wbuf[OSD0 + oc], wbuf[OBD0 + oc]), 0.f));
    }
    dst[g] = u.v;
  }
}

// ---- conv1 via MFMA implicit GEMM: 32->32 ch over padded 66^3 channel-last bf16 ----
__global__ __launch_bounds__(256) void conv1_mfma_k(
    const short* __restrict__ Pin, short* __restrict__ Pout,
    const float* __restrict__ wbuf, int wof, int sof, int bof,
    const float* __restrict__ m1f)
{
  __shared__ short ldsB[27 * 2 * 64 * 8];   // 54 KB: B-frags [tap][ochalf][lane][j]
  int tid = threadIdx.x;
  for (int e = tid; e < 27 * 1024; e += 256) {
    int t = e >> 10;
    int h = (e >> 9) & 1;
    int l = (e >> 3) & 63;
    int j = e & 7;
    int ic = ((l >> 4) << 3) + j;
    int oc = (h << 4) + (l & 15);
    ldsB[e] = (short)f2bf_bits(wbuf[wof + (oc * 32 + ic) * 27 + t]);
  }
  __syncthreads();

  int wave = tid >> 6, lane = tid & 63;
  int quad = lane >> 4, l15 = lane & 15;

  f32x4 acc[2][4][2];
  #pragma unroll
  for (int rr = 0; rr < 2; ++rr)
  #pragma unroll
  for (int tt = 0; tt < 4; ++tt)
  #pragma unroll
  for (int h = 0; h < 2; ++h) {
    f32x4 zf = {0.f, 0.f, 0.f, 0.f};
    acc[rr][tt][h] = zf;
  }

  int rowid0 = blockIdx.x * 8 + wave * 2;
  int abase[2], zz[2], yy[2];
  #pragma unroll
  for (int rr = 0; rr < 2; ++rr) {
    int rowid = rowid0 + rr;
    zz[rr] = rowid >> 6; yy[rr] = rowid & 63;
    abase[rr] = ((zz[rr] + 1) * PD + (yy[rr] + 1)) * PD + 1;
  }

  #pragma unroll 1
  for (int k = 0; k < 27; ++k) {
    int dz = k / 9, r9 = k - dz * 9, dy = r9 / 3, dx = r9 - dy * 3;
    int shift = (dz - 1) * PD2 + (dy - 1) * PD + (dx - 1);
    bf16x8 b0 = *(const bf16x8*)&ldsB[((k * 2 + 0) * 64 + lane) * 8];
    bf16x8 b1 = *(const bf16x8*)&ldsB[((k * 2 + 1) * 64 + lane) * 8];
    bf16x8 a[2][4];
    #pragma unroll
    for (int rr = 0; rr < 2; ++rr)
    #pragma unroll
    for (int tt = 0; tt < 4; ++tt) {
      int off = (abase[rr] + shift + tt * 16 + l15) * 32 + quad * 8;
      a[rr][tt] = *(const bf16x8*)(Pin + off);
    }
    #pragma unroll
    for (int rr = 0; rr < 2; ++rr)
    #pragma unroll
    for (int tt = 0; tt < 4; ++tt) {
      acc[rr][tt][0] = __builtin_amdgcn_mfma_f32_16x16x32_bf16(a[rr][tt], b0, acc[rr][tt][0], 0, 0, 0);
      acc[rr][tt][1] = __builtin_amdgcn_mfma_f32_16x16x32_bf16(a[rr][tt], b1, acc[rr][tt][1], 0, 0, 0);
    }
  }

  float sc[2] = { wbuf[sof + l15], wbuf[sof + 16 + l15] };
  float sh[2] = { wbuf[bof + l15], wbuf[bof + 16 + l15] };

  #pragma unroll
  for (int rr = 0; rr < 2; ++rr) {
    int mrow = (zz[rr] * 64 + yy[rr]) * 64;
    #pragma unroll
    for (int tt = 0; tt < 4; ++tt) {
      const float4 mv = *(const float4*)&m1f[mrow + tt * 16 + quad * 4];
      float mvr[4] = {mv.x, mv.y, mv.z, mv.w};
      #pragma unroll
      for (int h = 0; h < 2; ++h) {
        #pragma unroll
        for (int r = 0; r < 4; ++r) {
          float v = fmaxf(fmaf(acc[rr][tt][h][r], sc[h], sh[h]), 0.f) * mvr[r];
          int vox = abase[rr] + tt * 16 + quad * 4 + r;
          Pout[vox * 32 + h * 16 + l15] = (short)f2bf_bits(v);
        }
      }
    }
  }
}

// ---- trilinear sample from padded channel-last bf16 volume ----
__global__ __launch_bounds__(256) void sample_k(
    const void* __restrict__ coords, const int* __restrict__ flag,
    const short* __restrict__ vol, void* __restrict__ out)
{
  int p = blockIdx.x * 256 + threadIdx.x;
  if (p >= NPTS) return;
  int bf = *flag;
  float cx = ldIn(coords, 3l * p + 0, bf);
  float cy = ldIn(coords, 3l * p + 1, bf);
  float cz = ldIn(coords, 3l * p + 2, bf);
  float fx = (cx + 1.f) * 0.5f * 63.f;
  float fy = (cy + 1.f) * 0.5f * 63.f;
  float fz = (cz + 1.f) * 0.5f * 63.f;
  float x0f = floorf(fx), y0f = floorf(fy), z0f = floorf(fz);
  int x0 = (int)x0f, y0 = (int)y0f, z0 = (int)z0f;
  float tx = fx - x0f, ty = fy - y0f, tz = fz - z0f;
  int li[8]; float wt[8];
  #pragma unroll
  for (int dz = 0; dz < 2; ++dz)
  #pragma unroll
  for (int dy = 0; dy < 2; ++dy)
  #pragma unroll
  for (int dx = 0; dx < 2; ++dx) {
    int t = dz * 4 + dy * 2 + dx;
    int xi = x0 + dx, yi = y0 + dy, zi = z0 + dz;
    bool ok = (unsigned)xi < 64u && (unsigned)yi < 64u && (unsigned)zi < 64u;
    int xc = min(max(xi, 0), 63), yc = min(max(yi, 0), 63), zc = min(max(zi, 0), 63);
    li[t] = ((zc + 1) * PD + (yc + 1)) * PD + (xc + 1);
    float w = (dx ? tx : 1.f - tx) * (dy ? ty : 1.f - ty) * (dz ? tz : 1.f - tz);
    wt[t] = ok ? w : 0.f;
  }
  #pragma unroll
  for (int cc = 0; cc < 4; ++cc) {
    float s[8];
    #pragma unroll
    for (int j = 0; j < 8; ++j) s[j] = 0.f;
    #pragma unroll
    for (int t = 0; t < 8; ++t) {
      bf16x8 v = *(const bf16x8*)(vol + (size_t)li[t] * 32 + cc * 8);
      #pragma unroll
      for (int j = 0; j < 8; ++j) s[j] += bfbits2f(v[j]) * wt[t];
    }
    if (bf) {
      union { unsigned short us[8]; uint4 v; } u;
      #pragma unroll
      for (int j = 0; j < 8; ++j) u.us[j] = f2bf_bits(s[j]);
      ((uint4*)out)[p * 4 + cc] = u.v;
    } else {
      #pragma unroll
      for (int j = 0; j < 8; ++j) ((float*)out)[(size_t)p * 32 + cc * 8 + j] = s[j];
    }
  }
}

extern "C" void kernel_launch(void* const* d_in, const int* in_sizes, int n_in,
                              void* d_out, int out_size, void* d_ws, size_t ws_size,
                              hipStream_t stream)
{
  const void* xf     = d_in[0];
  const int*  mask   = (const int*)d_in[1];
  const void* coords = d_in[2];
  const void* w0a = d_in[3];
  const void* s0a = d_in[4];
  const void* b0a = d_in[5];
  const void* w0b = d_in[6];
  const void* s0b = d_in[7];
  const void* b0b = d_in[8];
  const void* wd0 = d_in[9];
  const void* sd0 = d_in[10];
  const void* bd0 = d_in[11];
  const void* w1a = d_in[12];
  const void* s1a = d_in[13];
  const void* b1a = d_in[14];
  const void* w1b = d_in[15];
  const void* s1b = d_in[16];
  const void* b1b = d_in[17];

  char* ws = (char*)d_ws;
  size_t cur = 0;
  auto alloc = [&](size_t bytes) -> size_t {
    size_t o = cur; cur = (cur + bytes + 255) & ~(size_t)255; return o;
  };
  size_t o_flag = alloc(4);
  size_t o_cnt  = alloc(4);
  size_t o_m1f  = alloc((size_t)M3 * 4);
  size_t o_wbuf = alloc((size_t)WTOT * 4);
  size_t o_T0B  = alloc((size_t)27 * 256 * 4);
  size_t o_TD0  = alloc((size_t)27 * 512 * 4);
  size_t o_list = alloc((size_t)N3 * 4);
  size_t o_P1   = alloc((size_t)PVOX * 32 * 2);   // padded 66^3 channel-last bf16
  size_t o_P2   = alloc((size_t)PVOX * 32 * 2);
  size_t o_h0p  = alloc((size_t)PH3 * 16 * 2);    // padded 130^3 channel-last bf16
  size_t o_h1p  = alloc((size_t)PH3 * 16 * 2);

  int*   flag = (int*)(ws + o_flag);
  int*   cnt  = (int*)(ws + o_cnt);
  float* m1f  = (float*)(ws + o_m1f);
  float* wbuf = (float*)(ws + o_wbuf);
  float* T0B  = (float*)(ws + o_T0B);
  float* TD0  = (float*)(ws + o_TD0);
  int*   list = (int*)(ws + o_list);
  short* P1   = (short*)(ws + o_P1);
  short* P2   = (short*)(ws + o_P2);
  short* h0p  = (short*)(ws + o_h0p);
  short* h1p  = (short*)(ws + o_h1p);

  hipMemsetAsync(cnt, 0, 4, stream);
  hipMemsetAsync(ws + o_P1, 0, 2ull * PVOX * 32 * 2, stream);     // P1+P2 contiguous
  hipMemsetAsync(ws + o_h0p, 0, 2ull * PH3 * 16 * 2, stream);     // h0p+h1p contiguous

  probe_k<<<1, 64, 0, stream>>>((const unsigned*)s0a, flag);
  cvt_k<<<(WTOT + 255) / 256, 256, 0, stream>>>(w0a, w0b, wd0, w1a, w1b,
                                                s0a, b0a, s0b, b0b, sd0, bd0,
                                                s1a, b1a, s1b, b1b, flag, wbuf);
  wtrans_k<<<(27 * 512 + 255) / 256, 256, 0, stream>>>(wbuf, T0B, TD0);
  masklist_k<<<256, 256, 0, stream>>>(mask, list, cnt);
  dsmask_k<<<M3 / 256, 256, 0, stream>>>(mask, m1f);

  conv0a_k<<<2048, 256, 0, stream>>>(xf, flag, mask, list, cnt, wbuf, h0p);
  conv0b_k<<<2048, 256, 0, stream>>>(h0p, list, cnt, T0B, wbuf, h1p);
  convd0_k<<<M3 / 256, 256, 0, stream>>>(h1p, m1f, TD0, wbuf, P1);

  conv1_mfma_k<<<512, 256, 0, stream>>>(P1, P2, wbuf, OW1A, OS1A, OB1A, m1f);
  conv1_mfma_k<<<512, 256, 0, stream>>>(P2, P1, wbuf, OW1B, OS1B, OB1B, m1f);

  sample_k<<<NPTS / 256, 256, 0, stream>>>(coords, flag, P1, d_out);
}